// Round 12
// baseline (488.317 us; speedup 1.0000x reference)
//
#include <hip/hip_runtime.h>
#include <hip/hip_cooperative_groups.h>
#include <math.h>

namespace cg = cooperative_groups;

#define BB 16
#define SS 16
#define VVV 64
#define EE 64
#define HHH 8
#define NLAYER 4
#define DFF_ 2048
#define LL 1024   /* S*V */
#define BL 16384  /* B*L */
#define PERL 131072  /* 64*2048 halves per layer of W1 (and W2); 32 tiles*4096 */

typedef __attribute__((ext_vector_type(8))) _Float16 half8;
typedef __attribute__((ext_vector_type(4))) _Float16 half4v;
typedef __attribute__((ext_vector_type(2))) _Float16 half2v;
typedef __attribute__((ext_vector_type(4))) float f32x4;

#if defined(__has_builtin)
#if __has_builtin(__builtin_amdgcn_fdot2)
#define HAVE_FDOT2 1
#endif
#endif

// XOR-swizzled index into row-major fp16 LDS tiles with 64-half (128 B) rows.
#define SW64(m, k)  (((m) << 6) + ((((k) >> 3) ^ ((m) & 7)) << 3) + ((k) & 7))

// Fragment-linear tile layout (64x64 fp16 = 8 frags of 512 halves):
//   A[m][k] -> frag = (m>>4)*2 + (k>>5); lane = ((k>>3)&3)*16 + (m&15); +(k&7)

// ---------------- prep: weights -> fp16 fragment-linear tiles (one dispatch) ----------
__global__ __launch_bounds__(256) void k_prep(
    const float* __restrict__ W1, const float* __restrict__ W2,
    const float* __restrict__ Wqkv, const float* __restrict__ Wo,
    const float* __restrict__ Wcomb,
    _Float16* __restrict__ w1f, _Float16* __restrict__ w2f,
    _Float16* __restrict__ wqkvf, _Float16* __restrict__ wof,
    _Float16* __restrict__ wcombt)
{
  __shared__ float t[64 * 65];
  int bx = blockIdx.x;
  int cc = threadIdx.x & 63, rr = threadIdx.x >> 6;

  if (bx >= 272) {  // Wcomb [80][64] -> wcombt [64][80]
    int r0 = (bx - 272) * 64;
#pragma unroll
    for (int i = 0; i < 16; i++) {
      int r = i * 4 + rr;
      if (r0 + r < 80) t[r * 65 + cc] = Wcomb[(size_t)(r0 + r) * 64 + cc];
    }
    __syncthreads();
#pragma unroll
    for (int i = 0; i < 16; i++) {
      int c = i * 4 + rr;
      if (r0 + c < 80) wcombt[(size_t)cc * 80 + r0 + c] = (_Float16)t[c * 65 + cc];
    }
    return;
  }

  const float* src; _Float16* dst; int astr;
  if (bx < 128) {        // W1 [64 k][2048 hid]: tile g = hid block
    int l = bx >> 5, g = bx & 31;
    src = W1 + (size_t)l * PERL + g * 64; astr = 2048;
    dst = w1f + (size_t)(l * 32 + g) * 4096;
  } else if (bx < 256) { // W2 [2048 k][64 n]: tile g = k block
    int j = bx - 128; int l = j >> 5, g = j & 31;
    src = W2 + (size_t)l * PERL + (size_t)g * 64 * 64; astr = 64;
    dst = w2f + (size_t)(l * 32 + g) * 4096;
  } else if (bx < 268) { // Wqkv [64 k][192 n]: 3 tiles per layer
    int j = bx - 256; int l = j / 3, g = j % 3;
    src = Wqkv + (size_t)l * 64 * 192 + g * 64; astr = 192;
    dst = wqkvf + (size_t)(l * 3 + g) * 4096;
  } else {               // Wo [64 k][64 n]
    int l = bx - 268;
    src = Wo + (size_t)l * 4096; astr = 64;
    dst = wof + (size_t)l * 4096;
  }
#pragma unroll
  for (int i = 0; i < 16; i++) {
    int a = i * 4 + rr;
    t[cc * 65 + a] = src[(size_t)a * astr + cc];  // t[m][k] = S[k][m]
  }
  __syncthreads();
#pragma unroll
  for (int it = 0; it < 2; it++) {
    int c = threadIdx.x + it * 256;
    int frag = c >> 6, lane = c & 63;
    int m = (frag >> 1) * 16 + (lane & 15);
    int k0 = (frag & 1) * 32 + (lane >> 4) * 8;
    const float* tr = &t[m * 65 + k0];
    half8 h;
#pragma unroll
    for (int j = 0; j < 8; j++) h[j] = (_Float16)tr[j];
    *(half8*)&dst[(size_t)c * 8] = h;
  }
}

struct NetParams {
  const float* features; const int* ovtag; const int* poiid;
  const float* W_raw; const float* b_raw;
  const float* ov_tab; const float* poi_tab;
  const _Float16* wcombt; const float* b_comb;
  const float* pos_tab; const float* type_tab;
  float* zm;
  const _Float16* wqkvf; const float* bqkv;
  const _Float16* wof;   const float* bo;
  const _Float16* w1f;   const _Float16* w2f;
  const float* b1; const float* b2;
  const float* ln1_s; const float* ln1_b;
  const float* ln2_s; const float* ln2_b;
  _Float16* kv;   // [set 2][which 2][B*8][1024][8]
  const float* Wh; const float* bh; float* out;
};

// ---------------- the whole network after prep: one cooperative kernel ----------------
__global__ __launch_bounds__(512) void k_net(NetParams P)
{
  cg::grid_group grid = cg::this_grid();
  __shared__ float    xf[4096];       // 16 KB fp32 residual x (block's 64 rows)
  __shared__ _Float16 xs[4096];       // 8 KB fp16 x, SW64
  __shared__ _Float16 qlds[4096];     // 8 KB q (then o), fragment-linear
  __shared__ float    ots[64 * 68];   // 17.4 KB GEMM epilogue staging
  __shared__ float    zs[1024];       // 4 KB zero-mask for this b
  __shared__ _Float16 wlds[3][8192];  // 48 KB FFN weight slots (W1c | W2c)
  __shared__ _Float16 hs[2][4096];    // 16 KB H dbuf

  int tid = threadIdx.x, bx = blockIdx.x;
  int wave = tid >> 6, lane = tid & 63;
  int quad = lane >> 4, l15 = lane & 15;
  int b = bx >> 4;

  // ======== phase 0: embed + comb GEMM + pos/type -> xf/xs; QKV layer 0 ========
  {
    constexpr int KP = 104;
    _Float16* As = &wlds[0][0];
    _Float16* Bs = &wlds[0][0] + 64 * KP;
    int m0 = bx * 64;
    for (int p = tid; p < 1536; p += 512) {
      int r = p / 24, s = p - r * 24; int c = s * 4;
      int row = m0 + r;
      float f0 = P.features[row * 3 + 0];
      float f1 = P.features[row * 3 + 1];
      float f2 = P.features[row * 3 + 2];
      if (s == 0) P.zm[row] = ((f0 + f1 + f2) == 0.f) ? 1.f : 0.f;
      half4v h;
#pragma unroll
      for (int j = 0; j < 4; j++) {
        int cc = c + j; float v;
        if (cc < 64) {
          v = P.b_raw[cc] + f0 * P.W_raw[cc] + f1 * P.W_raw[64 + cc] +
              f2 * P.W_raw[128 + cc];
        } else if (cc < 72) {
          int tt = P.ovtag[row]; v = (tt <= 0) ? 0.f : P.ov_tab[tt * 8 + cc - 64];
        } else if (cc < 80) {
          int tt = P.poiid[row]; v = (tt <= 0) ? 0.f : P.poi_tab[tt * 8 + cc - 72];
        } else v = 0.f;
        h[j] = (_Float16)v;
      }
      *(half4v*)&As[r * KP + c] = h;
    }
    for (int p = tid; p < 1536; p += 512) {
      int r = p / 24, s = p - r * 24; int c = s * 4;
      half4v h = (half4v){0, 0, 0, 0};
      if (c < 80) h = *(const half4v*)&P.wcombt[r * 80 + c];
      *(half4v*)&Bs[r * KP + c] = h;
    }
    __syncthreads();
    // 8 waves: wm = wave>>1 (m-16 tile), wn = wave&1 (n-32)
    int wm = wave >> 1, wn = wave & 1;
    f32x4 acc[2];
#pragma unroll
    for (int nt = 0; nt < 2; nt++) {
      float bv = P.b_comb[wn * 32 + nt * 16 + l15];
      acc[nt] = (f32x4){bv, bv, bv, bv};
    }
#pragma unroll
    for (int ks = 0; ks < 3; ks++) {
      half8 af = *(const half8*)&As[(wm * 16 + l15) * KP + ks * 32 + quad * 8];
#pragma unroll
      for (int nt = 0; nt < 2; nt++) {
        half8 bf = *(const half8*)&Bs[(wn * 32 + nt * 16 + l15) * KP +
                                      ks * 32 + quad * 8];
        acc[nt] = __builtin_amdgcn_mfma_f32_16x16x32_f16(af, bf, acc[nt], 0, 0, 0);
      }
    }
#pragma unroll
    for (int nt = 0; nt < 2; nt++)
#pragma unroll
      for (int r = 0; r < 4; r++) {
        int lrow = wm * 16 + quad * 4 + r;
        int col = wn * 32 + nt * 16 + l15;
        int l = (m0 + lrow) & (LL - 1);
        float v = acc[nt][r] + P.pos_tab[(l >> 6) * 64 + col] +
                  P.type_tab[(l & 63) * 64 + col];
        xf[lrow * 64 + col] = v;
        xs[SW64(lrow, col)] = (_Float16)v;
      }
  }
  __syncthreads();

  // shared QKV routine (reads xs; q->qlds, k/v->global set)
  auto qkv_all = [&](const _Float16* wq, const float* bq, int set) {
    int grp = wave >> 2, w4 = wave & 3;
    int wm = w4 >> 1, wn = w4 & 1;
    half8 af[2][2];
#pragma unroll
    for (int mt = 0; mt < 2; mt++)
#pragma unroll
      for (int ks = 0; ks < 2; ks++)
        af[mt][ks] = *(const half8*)&xs[SW64(wm * 32 + mt * 16 + l15,
                                             ks * 32 + quad * 8)];
    for (int nb = grp; nb < 3; nb += 2) {
      const _Float16* bt = wq + (size_t)nb * 4096;
      half8 bf[2][2];
#pragma unroll
      for (int nt = 0; nt < 2; nt++)
#pragma unroll
        for (int ks = 0; ks < 2; ks++)
          bf[nt][ks] = *(const half8*)&bt[(size_t)(((wn * 2 + nt) * 2 + ks) * 512) +
                                          lane * 8];
      f32x4 acc[2][2];
#pragma unroll
      for (int mt = 0; mt < 2; mt++)
#pragma unroll
        for (int nt = 0; nt < 2; nt++) {
          float bv = bq[nb * 64 + wn * 32 + nt * 16 + l15];
          acc[mt][nt] = (f32x4){bv, bv, bv, bv};
        }
#pragma unroll
      for (int ks = 0; ks < 2; ks++)
#pragma unroll
        for (int mt = 0; mt < 2; mt++)
#pragma unroll
          for (int nt = 0; nt < 2; nt++)
            acc[mt][nt] = __builtin_amdgcn_mfma_f32_16x16x32_f16(
                af[mt][ks], bf[nt][ks], acc[mt][nt], 0, 0, 0);
#pragma unroll
      for (int mt = 0; mt < 2; mt++)
#pragma unroll
        for (int nt = 0; nt < 2; nt++) {
          int col = wn * 32 + nt * 16 + l15;
          int h = col >> 3, d = col & 7;
#pragma unroll
          for (int r = 0; r < 4; r++) {
            int m = wm * 32 + mt * 16 + quad * 4 + r;
            _Float16 v = (_Float16)acc[mt][nt][r];
            if (nb == 0) {
              int frag = (m >> 4) * 2 + (h >> 2);
              int fl = (h & 3) * 16 + (m & 15);
              qlds[frag * 512 + fl * 8 + d] = v;
            } else {
              int which = nb - 1;
              int rb = (bx & 15) * 64 + m;
              P.kv[((size_t)((set * 2 + which) * (BB * 8) + b * 8 + h)) * 8192 +
                   rb * 8 + d] = v;
            }
          }
        }
    }
  };
  qkv_all(P.wqkvf, P.bqkv, 0);

  const float scale = 0.3535533905932738f;
  for (int l = 0; l < NLAYER; l++) {
    grid.sync();
    if (l == 0) {
      for (int p = tid; p < 1024; p += 512) zs[p] = P.zm[b * LL + p];
      __syncthreads();
    }
    // ======== attention: wave = head, lane = q-row; K/V from global (L2) ========
    {
      int h = wave;
      int frag = (lane >> 4) * 2 + (h >> 2);
      int fl = (h & 3) * 16 + (lane & 15);
      half8 qh = *(const half8*)&qlds[frag * 512 + fl * 8];
      const _Float16* kb = P.kv + ((size_t)(((l & 1) * 2 + 0) * (BB * 8) +
                                            b * 8 + h)) * 8192;
      const _Float16* vb = P.kv + ((size_t)(((l & 1) * 2 + 1) * (BB * 8) +
                                            b * 8 + h)) * 8192;
      int tqu = bx & 15;       // block-uniform t of this block's q rows
      int vq = lane;
      float m = -INFINITY, lsum = 0.f;
      float acc[8] = {0.f, 0.f, 0.f, 0.f, 0.f, 0.f, 0.f, 0.f};
      bool zmq = (zs[tqu * 64 + lane] != 0.f);
      auto attend = [&](int k) {
        if (zs[k] != 0.f) return;
        half8 kk = *(const half8*)&kb[k * 8];
        float s = 0.f;
#ifdef HAVE_FDOT2
#pragma unroll
        for (int j = 0; j < 4; j++) {
          half2v qa = (half2v){qh[2 * j], qh[2 * j + 1]};
          half2v ka = (half2v){kk[2 * j], kk[2 * j + 1]};
          s = __builtin_amdgcn_fdot2(qa, ka, s, false);
        }
#else
#pragma unroll
        for (int j = 0; j < 8; j++) s += (float)qh[j] * (float)kk[j];
#endif
        s *= scale;
        half8 vv = *(const half8*)&vb[k * 8];
        float nm = fmaxf(m, s);
        float rr = __expf(m - nm);
        float p = __expf(s - nm);
        lsum = lsum * rr + p;
#pragma unroll
        for (int d = 0; d < 8; d++) acc[d] = acc[d] * rr + p * (float)vv[d];
        m = nm;
      };
      if (!zmq) {
        for (int vv = 0; vv < 64; vv++) attend(tqu * 64 + vv);  // wave-uniform k
        for (int tt = 0; tt < 16; tt++) {
          if (tt == tqu) continue;
          attend(tt * 64 + vq);                                  // coalesced
        }
      }
      float inv = 1.f / lsum;
      half8 o;
#pragma unroll
      for (int d = 0; d < 8; d++) o[d] = (_Float16)(acc[d] * inv);
      *(half8*)&qlds[frag * 512 + fl * 8] = o;   // in place over q (own slots)
    }
    __syncthreads();
    // ======== o-proj -> ots ========
    {
      const _Float16* wof_l = P.wof + (size_t)l * 4096;
      const float* bo_l = P.bo + l * EE;
      int wm = wave >> 1, wn = wave & 1;
      f32x4 acc[2];
#pragma unroll
      for (int nt = 0; nt < 2; nt++) {
        float bv = bo_l[wn * 32 + nt * 16 + l15];
        acc[nt] = (f32x4){bv, bv, bv, bv};
      }
#pragma unroll
      for (int ks = 0; ks < 2; ks++) {
        half8 af = *(const half8*)&qlds[(wm * 2 + ks) * 512 + lane * 8];
#pragma unroll
        for (int nt = 0; nt < 2; nt++) {
          half8 bf = *(const half8*)&wof_l[(size_t)(((wn * 2 + nt) * 2 + ks) * 512) +
                                           lane * 8];
          acc[nt] = __builtin_amdgcn_mfma_f32_16x16x32_f16(af, bf, acc[nt], 0, 0, 0);
        }
      }
#pragma unroll
      for (int nt = 0; nt < 2; nt++)
#pragma unroll
        for (int r = 0; r < 4; r++)
          ots[(wm * 16 + quad * 4 + r) * 68 + wn * 32 + nt * 16 + l15] = acc[nt][r];
    }
    __syncthreads();
    // ======== residual + LN1 (8 waves x 8 rows) ========
    {
      const float* s1 = P.ln1_s + l * EE; const float* b1_ = P.ln1_b + l * EE;
      for (int i = 0; i < 8; i++) {
        int row = wave * 8 + i;
        float val = ots[row * 68 + lane] + xf[row * 64 + lane];
        float sum = val;
#pragma unroll
        for (int o = 32; o > 0; o >>= 1) sum += __shfl_xor(sum, o);
        float mean = sum * (1.f / 64.f);
        float d = val - mean;
        float sq = d * d;
#pragma unroll
        for (int o = 32; o > 0; o >>= 1) sq += __shfl_xor(sq, o);
        float xv = d * rsqrtf(sq * (1.f / 64.f) + 1e-5f) * s1[lane] + b1_[lane];
        xf[row * 64 + lane] = xv;
        xs[SW64(row, lane)] = (_Float16)xv;
      }
    }
    __syncthreads();
    // ======== FFN: 32 chunks of 64 hidden; weights LDS triple-buffered ========
    {
      const _Float16* w1l = P.w1f + (size_t)l * PERL;
      const _Float16* w2l = P.w2f + (size_t)l * PERL;
      const float* b1l = P.b1 + l * DFF_;
      const float* b2l = P.b2 + l * EE;
      int wh = wave >> 1, wm1 = wave & 1;   // GEMM1 roles
      int wm2 = wave >> 1, wn2 = wave & 1;  // GEMM2 roles
      half8 xb[2][2];
#pragma unroll
      for (int mt = 0; mt < 2; mt++)
#pragma unroll
        for (int ks = 0; ks < 2; ks++)
          xb[mt][ks] = *(const half8*)&xs[SW64(wm1 * 32 + mt * 16 + l15,
                                               ks * 32 + quad * 8)];
      f32x4 acc[2];
#pragma unroll
      for (int nt = 0; nt < 2; nt++) {
        float bv = b2l[wn2 * 32 + nt * 16 + l15];
        acc[nt] = (f32x4){bv, bv, bv, bv};
      }
      // stage chunk 0 into slot 0
      *(half8*)&wlds[0][tid * 8] = *(const half8*)&w1l[tid * 8];
      *(half8*)&wlds[0][4096 + tid * 8] = *(const half8*)&w2l[tid * 8];
      __syncthreads();
      for (int c = 0; c < 32; c++) {
        int slot = c % 3, nslot = (c + 1) % 3;
        // GEMM1: Ht[64 hid][64 m]
        f32x4 hacc[2] = {(f32x4){0.f, 0.f, 0.f, 0.f}, (f32x4){0.f, 0.f, 0.f, 0.f}};
#pragma unroll
        for (int ks = 0; ks < 2; ks++) {
          half8 a1 = *(const half8*)&wlds[slot][(wh * 2 + ks) * 512 + lane * 8];
#pragma unroll
          for (int mt = 0; mt < 2; mt++)
            hacc[mt] = __builtin_amdgcn_mfma_f32_16x16x32_f16(a1, xb[mt][ks],
                                                              hacc[mt], 0, 0, 0);
        }
        float4 bb = *(const float4*)&b1l[c * 64 + wh * 16 + quad * 4];
#pragma unroll
        for (int mt = 0; mt < 2; mt++) {
          f32x4 hv = hacc[mt];
          half4v hp = (half4v){
              (_Float16)fmaxf(hv[0] + bb.x, 0.f), (_Float16)fmaxf(hv[1] + bb.y, 0.f),
              (_Float16)fmaxf(hv[2] + bb.z, 0.f), (_Float16)fmaxf(hv[3] + bb.w, 0.f)};
          *(half4v*)&hs[c & 1][SW64(wm1 * 32 + mt * 16 + l15,
                                    wh * 16 + quad * 4)] = hp;
        }
        if (c < 31) {   // stage chunk c+1
          *(half8*)&wlds[nslot][tid * 8] =
              *(const half8*)&w1l[(size_t)(c + 1) * 4096 + tid * 8];
          *(half8*)&wlds[nslot][4096 + tid * 8] =
              *(const half8*)&w2l[(size_t)(c + 1) * 4096 + tid * 8];
        }
        __syncthreads();
        // GEMM2: acc += H @ W2c
#pragma unroll
        for (int ks = 0; ks < 2; ks++) {
          half8 a2 = *(const half8*)&hs[c & 1][SW64(wm2 * 16 + l15,
                                                    ks * 32 + quad * 8)];
#pragma unroll
          for (int nt = 0; nt < 2; nt++) {
            half8 b2w = *(const half8*)&wlds[slot][4096 +
                ((wn2 * 2 + nt) * 2 + ks) * 512 + lane * 8];
            acc[nt] = __builtin_amdgcn_mfma_f32_16x16x32_f16(a2, b2w, acc[nt],
                                                             0, 0, 0);
          }
        }
      }
      __syncthreads();
#pragma unroll
      for (int nt = 0; nt < 2; nt++)
#pragma unroll
        for (int r = 0; r < 4; r++)
          ots[(wm2 * 16 + quad * 4 + r) * 68 + wn2 * 32 + nt * 16 + l15] =
              acc[nt][r];
    }
    __syncthreads();
    // ======== residual + LN2 ========
    {
      const float* s2 = P.ln2_s + l * EE; const float* b2_ = P.ln2_b + l * EE;
      for (int i = 0; i < 8; i++) {
        int row = wave * 8 + i;
        float val = ots[row * 68 + lane] + xf[row * 64 + lane];
        float sum = val;
#pragma unroll
        for (int o = 32; o > 0; o >>= 1) sum += __shfl_xor(sum, o);
        float mean = sum * (1.f / 64.f);
        float d = val - mean;
        float sq = d * d;
#pragma unroll
        for (int o = 32; o > 0; o >>= 1) sq += __shfl_xor(sq, o);
        float xv = d * rsqrtf(sq * (1.f / 64.f) + 1e-5f) * s2[lane] + b2_[lane];
        xf[row * 64 + lane] = xv;
        xs[SW64(row, lane)] = (_Float16)xv;
      }
    }
    __syncthreads();
    if (l < NLAYER - 1) {
      qkv_all(P.wqkvf + (size_t)(l + 1) * 3 * 4096, P.bqkv + (l + 1) * 192,
              (l + 1) & 1);
    } else {
      // fused head: blocks owning t==15 rows
      if ((bx & 15) == 15 && tid < 192) {
        int v = tid / 3, j = tid - v * 3;
        float a = P.bh[j];
        for (int e = 0; e < 64; e++) a += xf[v * 64 + e] * P.Wh[e * 3 + j];
        P.out[((size_t)(b * 64 + v)) * 3 + j] = a;
      }
    }
  }
}

extern "C" void kernel_launch(void* const* d_in, const int* in_sizes, int n_in,
                              void* d_out, int out_size, void* d_ws, size_t ws_size,
                              hipStream_t stream) {
  const float* features = (const float*)d_in[0];
  const int*   ovtag    = (const int*)d_in[1];
  const int*   poiid    = (const int*)d_in[2];
  const float* W_raw    = (const float*)d_in[3];
  const float* b_raw    = (const float*)d_in[4];
  const float* pos_tab  = (const float*)d_in[5];
  const float* type_tab = (const float*)d_in[6];
  const float* poi_tab  = (const float*)d_in[7];
  const float* ov_tab   = (const float*)d_in[8];
  const float* W_comb   = (const float*)d_in[9];
  const float* b_comb   = (const float*)d_in[10];
  const float* Wqkv     = (const float*)d_in[11];
  const float* bqkv     = (const float*)d_in[12];
  const float* Wo       = (const float*)d_in[13];
  const float* bo       = (const float*)d_in[14];
  const float* ln1_s    = (const float*)d_in[15];
  const float* ln1_b    = (const float*)d_in[16];
  const float* W1       = (const float*)d_in[17];
  const float* b1       = (const float*)d_in[18];
  const float* W2       = (const float*)d_in[19];
  const float* b2       = (const float*)d_in[20];
  const float* ln2_s    = (const float*)d_in[21];
  const float* ln2_b    = (const float*)d_in[22];
  const float* W_head   = (const float*)d_in[23];
  const float* b_head   = (const float*)d_in[24];
  float* out = (float*)d_out;
  float* ws  = (float*)d_ws;

  float* zm = ws;                                       // BL
  _Float16* kv     = (_Float16*)(zm + BL);              // 2 sets x 2 x BL*64
  _Float16* wcombt = kv + 4 * (size_t)BL * 64;          // 64*80
  _Float16* w1f    = wcombt + 5120;                     // NL*PERL
  _Float16* w2f    = w1f + (size_t)NLAYER * PERL;       // NL*PERL
  _Float16* wqkvf  = w2f + (size_t)NLAYER * PERL;       // NL*3*4096
  _Float16* wof    = wqkvf + (size_t)NLAYER * 3 * 4096; // NL*4096

  k_prep<<<274, 256, 0, stream>>>(W1, W2, Wqkv, Wo, W_comb,
                                  w1f, w2f, wqkvf, wof, wcombt);
  NetParams p;
  p.features = features; p.ovtag = ovtag; p.poiid = poiid;
  p.W_raw = W_raw; p.b_raw = b_raw; p.ov_tab = ov_tab; p.poi_tab = poi_tab;
  p.wcombt = wcombt; p.b_comb = b_comb; p.pos_tab = pos_tab; p.type_tab = type_tab;
  p.zm = zm; p.wqkvf = wqkvf; p.bqkv = bqkv; p.wof = wof; p.bo = bo;
  p.w1f = w1f; p.w2f = w2f; p.b1 = b1; p.b2 = b2;
  p.ln1_s = ln1_s; p.ln1_b = ln1_b; p.ln2_s = ln2_s; p.ln2_b = ln2_b;
  p.kv = kv; p.Wh = W_head; p.bh = b_head; p.out = out;
  void* args[] = {&p};
  hipLaunchCooperativeKernel((const void*)k_net, dim3(256), dim3(512), args, 0,
                             stream);
}

// Round 13
// 340.177 us; speedup vs baseline: 1.4355x; 1.4355x over previous
//
#include <hip/hip_runtime.h>
#include <math.h>

#define BB 16
#define SS 16
#define VVV 64
#define EE 64
#define HHH 8
#define NLAYER 4
#define DFF_ 2048
#define LL 1024   /* S*V */
#define BL 16384  /* B*L */
#define PERL 131072  /* 64*2048 halves per layer of W1 (and W2); 32 tiles*4096 */

typedef __attribute__((ext_vector_type(8))) _Float16 half8;
typedef __attribute__((ext_vector_type(4))) _Float16 half4v;
typedef __attribute__((ext_vector_type(2))) _Float16 half2v;
typedef __attribute__((ext_vector_type(4))) float f32x4;

#if defined(__has_builtin)
#if __has_builtin(__builtin_amdgcn_fdot2)
#define HAVE_FDOT2 1
#endif
#endif

// XOR-swizzled index into row-major fp16 LDS tiles with 64-half (128 B) rows.
#define SW64(m, k)  (((m) << 6) + ((((k) >> 3) ^ ((m) & 7)) << 3) + ((k) & 7))

// Fragment-linear tile layout (64x64 fp16 = 8 frags of 512 halves):
//   A[m][k] -> frag = (m>>4)*2 + (k>>5); lane = ((k>>3)&3)*16 + (m&15); +(k&7)

__device__ __forceinline__ float dot8(half8 a, half8 b) {
  float s = 0.f;
#ifdef HAVE_FDOT2
#pragma unroll
  for (int j = 0; j < 4; j++) {
    half2v x = (half2v){a[2 * j], a[2 * j + 1]};
    half2v y = (half2v){b[2 * j], b[2 * j + 1]};
    s = __builtin_amdgcn_fdot2(x, y, s, false);
  }
#else
#pragma unroll
  for (int j = 0; j < 8; j++) s += (float)a[j] * (float)b[j];
#endif
  return s;
}

// ---------------- prep: weights -> fp16 fragment-linear tiles (one dispatch) ----------
__global__ __launch_bounds__(256) void k_prep(
    const float* __restrict__ W1, const float* __restrict__ W2,
    const float* __restrict__ Wqkv, const float* __restrict__ Wo,
    const float* __restrict__ Wcomb,
    _Float16* __restrict__ w1f, _Float16* __restrict__ w2f,
    _Float16* __restrict__ wqkvf, _Float16* __restrict__ wof,
    _Float16* __restrict__ wcombt)
{
  __shared__ float t[64 * 65];
  int bx = blockIdx.x;
  int cc = threadIdx.x & 63, rr = threadIdx.x >> 6;

  if (bx >= 272) {  // Wcomb [80][64] -> wcombt [64][80]
    int r0 = (bx - 272) * 64;
#pragma unroll
    for (int i = 0; i < 16; i++) {
      int r = i * 4 + rr;
      if (r0 + r < 80) t[r * 65 + cc] = Wcomb[(size_t)(r0 + r) * 64 + cc];
    }
    __syncthreads();
#pragma unroll
    for (int i = 0; i < 16; i++) {
      int c = i * 4 + rr;
      if (r0 + c < 80) wcombt[(size_t)cc * 80 + r0 + c] = (_Float16)t[c * 65 + cc];
    }
    return;
  }

  const float* src; _Float16* dst; int astr;
  if (bx < 128) {        // W1 [64 k][2048 hid]: tile g = hid block
    int l = bx >> 5, g = bx & 31;
    src = W1 + (size_t)l * PERL + g * 64; astr = 2048;
    dst = w1f + (size_t)(l * 32 + g) * 4096;
  } else if (bx < 256) { // W2 [2048 k][64 n]: tile g = k block
    int j = bx - 128; int l = j >> 5, g = j & 31;
    src = W2 + (size_t)l * PERL + (size_t)g * 64 * 64; astr = 64;
    dst = w2f + (size_t)(l * 32 + g) * 4096;
  } else if (bx < 268) { // Wqkv [64 k][192 n]: 3 tiles per layer
    int j = bx - 256; int l = j / 3, g = j % 3;
    src = Wqkv + (size_t)l * 64 * 192 + g * 64; astr = 192;
    dst = wqkvf + (size_t)(l * 3 + g) * 4096;
  } else {               // Wo [64 k][64 n]
    int l = bx - 268;
    src = Wo + (size_t)l * 4096; astr = 64;
    dst = wof + (size_t)l * 4096;
  }
#pragma unroll
  for (int i = 0; i < 16; i++) {
    int a = i * 4 + rr;
    t[cc * 65 + a] = src[(size_t)a * astr + cc];  // t[m][k] = S[k][m]
  }
  __syncthreads();
#pragma unroll
  for (int it = 0; it < 2; it++) {
    int c = threadIdx.x + it * 256;
    int frag = c >> 6, lane = c & 63;
    int m = (frag >> 1) * 16 + (lane & 15);
    int k0 = (frag & 1) * 32 + (lane >> 4) * 8;
    const float* tr = &t[m * 65 + k0];
    half8 h;
#pragma unroll
    for (int j = 0; j < 8; j++) h[j] = (_Float16)tr[j];
    *(half8*)&dst[(size_t)c * 8] = h;
  }
}

// ---- QKV GEMM body (64-row tile, caller supplies wave roles); ALL head-major stores ----
// q -> qbuf[(b*8+h)*1024 + rb][8];  k/v -> kvbuf set slot.
__device__ __forceinline__ void qkv_nb(
    const half8 (&af)[2][2], const _Float16* __restrict__ wqkvf,
    const float* __restrict__ bqkv, _Float16* __restrict__ qbuf,
    _Float16* __restrict__ kvbuf, int set,
    int bx, int nb, int wm, int wn, int lane)
{
  int quad = lane >> 4, l15 = lane & 15;
  const _Float16* bt = wqkvf + (size_t)nb * 4096;
  half8 bf[2][2];
#pragma unroll
  for (int nt = 0; nt < 2; nt++)
#pragma unroll
    for (int ks = 0; ks < 2; ks++)
      bf[nt][ks] = *(const half8*)&bt[(size_t)(((wn * 2 + nt) * 2 + ks) * 512) +
                                      lane * 8];
  f32x4 acc[2][2];
#pragma unroll
  for (int mt = 0; mt < 2; mt++)
#pragma unroll
    for (int nt = 0; nt < 2; nt++) {
      float bv = bqkv[nb * 64 + wn * 32 + nt * 16 + l15];
      acc[mt][nt] = (f32x4){bv, bv, bv, bv};
    }
#pragma unroll
  for (int ks = 0; ks < 2; ks++)
#pragma unroll
    for (int mt = 0; mt < 2; mt++)
#pragma unroll
      for (int nt = 0; nt < 2; nt++)
        acc[mt][nt] = __builtin_amdgcn_mfma_f32_16x16x32_f16(
            af[mt][ks], bf[nt][ks], acc[mt][nt], 0, 0, 0);
  _Float16* dst = (nb == 0)
      ? qbuf
      : kvbuf + ((size_t)((set * 2 + nb - 1) * (BB * 8))) * 8192;
#pragma unroll
  for (int mt = 0; mt < 2; mt++)
#pragma unroll
    for (int nt = 0; nt < 2; nt++) {
      int col = wn * 32 + nt * 16 + l15;
      int h = col >> 3, d = col & 7;
#pragma unroll
      for (int r = 0; r < 4; r++) {
        int row = bx * 64 + wm * 32 + mt * 16 + quad * 4 + r;
        int b = row >> 10, rb = row & 1023;
        dst[((size_t)(b * 8 + h) * 1024 + rb) * 8 + d] = (_Float16)acc[mt][nt][r];
      }
    }
}

// ------- fused embed + comb GEMM + pos/type + QKV(layer0): writes x1, zm, q/k/v -------
__global__ __launch_bounds__(256) void k_embqkv(
    const float* __restrict__ features, const int* __restrict__ ovtag,
    const int* __restrict__ poiid, const float* __restrict__ W_raw,
    const float* __restrict__ b_raw, const float* __restrict__ ov_tab,
    const float* __restrict__ poi_tab, const _Float16* __restrict__ wcombt,
    const float* __restrict__ b_comb, const float* __restrict__ pos_tab,
    const float* __restrict__ type_tab, float* __restrict__ x1,
    float* __restrict__ zm, const _Float16* __restrict__ wqkvf,
    const float* __restrict__ bqkv, _Float16* __restrict__ qbuf,
    _Float16* __restrict__ kvbuf)
{
  constexpr int KP = 104;
  __shared__ _Float16 As[64 * KP];
  __shared__ _Float16 Bs[64 * KP];
  __shared__ _Float16 xs[4096];
  int tid = threadIdx.x;
  int bx = blockIdx.x;
  int m0 = bx * 64;
  int wave = tid >> 6, lane = tid & 63, quad = lane >> 4, l15 = lane & 15;
  int wm = wave >> 1, wn = wave & 1;
  for (int p = tid; p < 1536; p += 256) {
    int r = p / 24, s = p - r * 24; int c = s * 4;
    int row = m0 + r;
    float f0 = features[row * 3 + 0];
    float f1 = features[row * 3 + 1];
    float f2 = features[row * 3 + 2];
    if (s == 0) zm[row] = ((f0 + f1 + f2) == 0.f) ? 1.f : 0.f;
    half4v h;
#pragma unroll
    for (int j = 0; j < 4; j++) {
      int cc = c + j; float v;
      if (cc < 64) {
        v = b_raw[cc] + f0 * W_raw[cc] + f1 * W_raw[64 + cc] + f2 * W_raw[128 + cc];
      } else if (cc < 72) {
        int tt = ovtag[row]; v = (tt <= 0) ? 0.f : ov_tab[tt * 8 + cc - 64];
      } else if (cc < 80) {
        int tt = poiid[row]; v = (tt <= 0) ? 0.f : poi_tab[tt * 8 + cc - 72];
      } else v = 0.f;
      h[j] = (_Float16)v;
    }
    *(half4v*)&As[r * KP + c] = h;
  }
  for (int p = tid; p < 1536; p += 256) {
    int r = p / 24, s = p - r * 24; int c = s * 4;
    half4v h = (half4v){0, 0, 0, 0};
    if (c < 80) h = *(const half4v*)&wcombt[r * 80 + c];
    *(half4v*)&Bs[r * KP + c] = h;
  }
  __syncthreads();
  f32x4 acc[2][2];
#pragma unroll
  for (int mt = 0; mt < 2; mt++)
#pragma unroll
    for (int nt = 0; nt < 2; nt++) {
      float bv = b_comb[wn * 32 + nt * 16 + l15];
      acc[mt][nt] = (f32x4){bv, bv, bv, bv};
    }
#pragma unroll
  for (int ks = 0; ks < 3; ks++) {
    half8 af[2], bf[2];
#pragma unroll
    for (int mt = 0; mt < 2; mt++)
      af[mt] = *(const half8*)&As[(wm * 32 + mt * 16 + l15) * KP + ks * 32 + quad * 8];
#pragma unroll
    for (int nt = 0; nt < 2; nt++)
      bf[nt] = *(const half8*)&Bs[(wn * 32 + nt * 16 + l15) * KP + ks * 32 + quad * 8];
#pragma unroll
    for (int mt = 0; mt < 2; mt++)
#pragma unroll
      for (int nt = 0; nt < 2; nt++)
        acc[mt][nt] = __builtin_amdgcn_mfma_f32_16x16x32_f16(af[mt], bf[nt],
                                                             acc[mt][nt], 0, 0, 0);
  }
#pragma unroll
  for (int mt = 0; mt < 2; mt++)
#pragma unroll
    for (int nt = 0; nt < 2; nt++)
#pragma unroll
      for (int r = 0; r < 4; r++) {
        int lrow = wm * 32 + mt * 16 + quad * 4 + r;
        int row = m0 + lrow;
        int col = wn * 32 + nt * 16 + l15;
        int l = row & (LL - 1);
        float v = acc[mt][nt][r] +
            pos_tab[(l >> 6) * 64 + col] + type_tab[(l & 63) * 64 + col];
        x1[(size_t)row * 64 + col] = v;
        xs[SW64(lrow, col)] = (_Float16)v;
      }
  __syncthreads();
  half8 af[2][2];
#pragma unroll
  for (int mt = 0; mt < 2; mt++)
#pragma unroll
    for (int ks = 0; ks < 2; ks++)
      af[mt][ks] = *(const half8*)&xs[SW64(wm * 32 + mt * 16 + l15,
                                           ks * 32 + quad * 8)];
  for (int nb = 0; nb < 3; nb++)
    qkv_nb(af, wqkvf, bqkv, qbuf, kvbuf, 0, bx, nb, wm, wn, lane);
}

// ---- per-layer merged kernel: attention + o-proj + LN1 + FFN + LN2 + next-QKV/head ----
// grid 256 x 512 thr; 68 KB LDS -> 2 blocks/CU. K/V direct from L2, grouped loads.
__global__ __launch_bounds__(512, 4) void k_layer3(
    const _Float16* __restrict__ qbuf, _Float16* __restrict__ kvbuf, int l,
    const _Float16* __restrict__ wof, const float* __restrict__ bo,
    float* __restrict__ x1,
    const float* __restrict__ ln1_s, const float* __restrict__ ln1_b,
    const _Float16* __restrict__ w1f, const _Float16* __restrict__ w2f,
    const float* __restrict__ b1, const float* __restrict__ b2,
    const float* __restrict__ ln2_s, const float* __restrict__ ln2_b,
    const _Float16* __restrict__ wqkvf, const float* __restrict__ bqkv,
    _Float16* __restrict__ qout, int doqkv,
    const float* __restrict__ Wh, const float* __restrict__ bh,
    float* __restrict__ out, const float* __restrict__ zm)
{
  __shared__ float    xf[4096];              // 16 KB fp32 residual x
  __shared__ _Float16 xs[4096];              // 8 KB fp16 x, SW64
  __shared__ _Float16 qlds[4096];            // 8 KB attention output, frag-linear
  __shared__ float    zb[1024];              // 4 KB additive mask bias
  __shared__ __align__(16) float smem_u[8192];  // 32 KB: hs (4x4096 f16) | ots (64x68 f32)
  _Float16* hsu = (_Float16*)smem_u;
  float* ots = smem_u;

  int tid = threadIdx.x, bx = blockIdx.x;
  int wave = tid >> 6, lane = tid & 63;
  int quad = lane >> 4, l15 = lane & 15;
  int b = bx >> 4, tq = bx & 15;

  // ======== attention (wave = head, lane = q-row in block's 64 rows) ========
  for (int p = tid; p < 1024; p += 512)
    zb[p] = (zm[b * LL + p] != 0.f) ? -1e30f : 0.f;
  __syncthreads();
  {
    int h = wave;
    half8 qh = *(const half8*)&qbuf[((size_t)(b * 8 + h) * 1024 +
                                     tq * 64 + lane) * 8];
    const _Float16* kb = kvbuf + ((size_t)((((l & 1) * 2 + 0) * (BB * 8)) +
                                           b * 8 + h)) * 8192;
    const _Float16* vb = kvbuf + ((size_t)((((l & 1) * 2 + 1) * (BB * 8)) +
                                           b * 8 + h)) * 8192;
    const float scale = 0.3535533905932738f;
    float m = -INFINITY, lsum = 0.f;
    float acc[8] = {0.f, 0.f, 0.f, 0.f, 0.f, 0.f, 0.f, 0.f};
    bool zmq = (zb[tq * 64 + lane] < -1.f);
    if (!zmq) {
      // same-t: 16 groups of 4 (wave-uniform keys); unconditional loads
      for (int g = 0; g < 16; g++) {
        half8 kk[4], vv[4]; float s[4];
#pragma unroll
        for (int j = 0; j < 4; j++) {
          int k = tq * 64 + g * 4 + j;
          kk[j] = *(const half8*)&kb[k * 8];
          vv[j] = *(const half8*)&vb[k * 8];
        }
#pragma unroll
        for (int j = 0; j < 4; j++)
          s[j] = dot8(qh, kk[j]) * scale + zb[tq * 64 + g * 4 + j];
        float gm = fmaxf(fmaxf(s[0], s[1]), fmaxf(s[2], s[3]));
        float nm = fmaxf(m, gm);
        float r = __expf(m - nm);
        float p0 = __expf(s[0] - nm), p1 = __expf(s[1] - nm);
        float p2 = __expf(s[2] - nm), p3 = __expf(s[3] - nm);
        lsum = lsum * r + (p0 + p1) + (p2 + p3);
#pragma unroll
        for (int d = 0; d < 8; d++)
          acc[d] = acc[d] * r + p0 * (float)vv[0][d] + p1 * (float)vv[1][d] +
                   p2 * (float)vv[2][d] + p3 * (float)vv[3][d];
        m = nm;
      }
      // same-v: 4 groups of 4 over tt (coalesced); tq entry biased out
      for (int g = 0; g < 4; g++) {
        half8 kk[4], vv[4]; float s[4];
#pragma unroll
        for (int j = 0; j < 4; j++) {
          int tt = g * 4 + j;
          int k = tt * 64 + lane;
          kk[j] = *(const half8*)&kb[k * 8];
          vv[j] = *(const half8*)&vb[k * 8];
          s[j] = (tt == tq) ? -1e30f : zb[k];
        }
#pragma unroll
        for (int j = 0; j < 4; j++)
          s[j] += dot8(qh, kk[j]) * scale;
        float gm = fmaxf(fmaxf(s[0], s[1]), fmaxf(s[2], s[3]));
        float nm = fmaxf(m, gm);
        float r = __expf(m - nm);
        float p0 = __expf(s[0] - nm), p1 = __expf(s[1] - nm);
        float p2 = __expf(s[2] - nm), p3 = __expf(s[3] - nm);
        lsum = lsum * r + (p0 + p1) + (p2 + p3);
#pragma unroll
        for (int d = 0; d < 8; d++)
          acc[d] = acc[d] * r + p0 * (float)vv[0][d] + p1 * (float)vv[1][d] +
                   p2 * (float)vv[2][d] + p3 * (float)vv[3][d];
        m = nm;
      }
    }
    float inv = 1.f / lsum;
    half8 o;
#pragma unroll
    for (int d = 0; d < 8; d++) o[d] = (_Float16)(acc[d] * inv);
    int frag = (lane >> 4) * 2 + (h >> 2);
    int fl = (h & 3) * 16 + (lane & 15);
    *(half8*)&qlds[frag * 512 + fl * 8] = o;
  }
  __syncthreads();
  // ======== o-proj -> ots ========
  {
    int wm = wave >> 1, wn = wave & 1;
    f32x4 acc[2];
#pragma unroll
    for (int nt = 0; nt < 2; nt++) {
      float bv = bo[wn * 32 + nt * 16 + l15];
      acc[nt] = (f32x4){bv, bv, bv, bv};
    }
#pragma unroll
    for (int ks = 0; ks < 2; ks++) {
      half8 af = *(const half8*)&qlds[(wm * 2 + ks) * 512 + lane * 8];
#pragma unroll
      for (int nt = 0; nt < 2; nt++) {
        half8 bf = *(const half8*)&wof[(size_t)(((wn * 2 + nt) * 2 + ks) * 512) +
                                       lane * 8];
        acc[nt] = __builtin_amdgcn_mfma_f32_16x16x32_f16(af, bf, acc[nt], 0, 0, 0);
      }
    }
#pragma unroll
    for (int nt = 0; nt < 2; nt++)
#pragma unroll
      for (int r = 0; r < 4; r++)
        ots[(wm * 16 + quad * 4 + r) * 68 + wn * 32 + nt * 16 + l15] = acc[nt][r];
  }
  __syncthreads();
  // ======== residual + LN1 ========
  for (int i = 0; i < 8; i++) {
    int row = wave * 8 + i;
    size_t off = (size_t)(bx * 64 + row) * 64 + lane;
    float val = ots[row * 68 + lane] + x1[off];
    float sum = val;
#pragma unroll
    for (int o = 32; o > 0; o >>= 1) sum += __shfl_xor(sum, o);
    float mean = sum * (1.f / 64.f);
    float d = val - mean;
    float sq = d * d;
#pragma unroll
    for (int o = 32; o > 0; o >>= 1) sq += __shfl_xor(sq, o);
    float xv = d * rsqrtf(sq * (1.f / 64.f) + 1e-5f) * ln1_s[lane] + ln1_b[lane];
    xf[row * 64 + lane] = xv;
    xs[SW64(row, lane)] = (_Float16)xv;
  }
  __syncthreads();
  // ======== FFN (2 groups x 4 waves; groups interleave chunks; reg prefetch) ========
  {
    int grp = wave >> 2, w4 = wave & 3;
    int wm = w4 >> 1, wn = w4 & 1;
    half8 xb[2][2];
#pragma unroll
    for (int mt = 0; mt < 2; mt++)
#pragma unroll
      for (int ks = 0; ks < 2; ks++)
        xb[mt][ks] = *(const half8*)&xs[SW64(wn * 32 + mt * 16 + l15,
                                             ks * 32 + quad * 8)];
    f32x4 acc[2][2];
#pragma unroll
    for (int mt = 0; mt < 2; mt++)
#pragma unroll
      for (int nt = 0; nt < 2; nt++) {
        float bv = (grp == 0) ? b2[wn * 32 + nt * 16 + l15] : 0.f;
        acc[mt][nt] = (f32x4){bv, bv, bv, bv};
      }
    half8 a1x[2][2], b2x[2][2], a1y[2][2], b2y[2][2];
    auto loadw = [&](int g, half8 (&a1)[2][2], half8 (&b2w)[2][2]) {
      const _Float16* w1t_ = w1f + (size_t)g * 4096;
      const _Float16* w2t_ = w2f + (size_t)g * 4096;
#pragma unroll
      for (int ht = 0; ht < 2; ht++)
#pragma unroll
        for (int ks = 0; ks < 2; ks++)
          a1[ht][ks] = *(const half8*)&w1t_[(size_t)(((wm * 2 + ht) * 2 + ks) * 512)
                                            + lane * 8];
#pragma unroll
      for (int nt = 0; nt < 2; nt++)
#pragma unroll
        for (int ks = 0; ks < 2; ks++)
          b2w[nt][ks] = *(const half8*)&w2t_[(size_t)(((wn * 2 + nt) * 2 + ks) * 512)
                                             + lane * 8];
    };
    auto step = [&](const half8 (&a1)[2][2], const half8 (&b2w)[2][2],
                    _Float16* hsbuf, int g) {
      f32x4 hacc[2][2];
#pragma unroll
      for (int ht = 0; ht < 2; ht++)
#pragma unroll
        for (int mt = 0; mt < 2; mt++) hacc[ht][mt] = (f32x4){0.f, 0.f, 0.f, 0.f};
#pragma unroll
      for (int ks = 0; ks < 2; ks++)
#pragma unroll
        for (int ht = 0; ht < 2; ht++)
#pragma unroll
          for (int mt = 0; mt < 2; mt++)
            hacc[ht][mt] = __builtin_amdgcn_mfma_f32_16x16x32_f16(
                a1[ht][ks], xb[mt][ks], hacc[ht][mt], 0, 0, 0);
#pragma unroll
      for (int ht = 0; ht < 2; ht++) {
        float4 bb = *(const float4*)&b1[g * 64 + wm * 32 + ht * 16 + quad * 4];
#pragma unroll
        for (int mt = 0; mt < 2; mt++) {
          f32x4 hv = hacc[ht][mt];
          half4v hp = (half4v){
              (_Float16)fmaxf(hv[0] + bb.x, 0.f),
              (_Float16)fmaxf(hv[1] + bb.y, 0.f),
              (_Float16)fmaxf(hv[2] + bb.z, 0.f),
              (_Float16)fmaxf(hv[3] + bb.w, 0.f)};
          *(half4v*)&hsbuf[SW64(wn * 32 + mt * 16 + l15,
                                wm * 32 + ht * 16 + quad * 4)] = hp;
        }
      }
      __syncthreads();
#pragma unroll
      for (int ks = 0; ks < 2; ks++)
#pragma unroll
        for (int mt = 0; mt < 2; mt++) {
          half8 a2 = *(const half8*)&hsbuf[SW64(wm * 32 + mt * 16 + l15,
                                                ks * 32 + quad * 8)];
#pragma unroll
          for (int nt = 0; nt < 2; nt++)
            acc[mt][nt] = __builtin_amdgcn_mfma_f32_16x16x32_f16(
                a2, b2w[nt][ks], acc[mt][nt], 0, 0, 0);
        }
    };
    loadw(grp, a1x, b2x);
    for (int ii = 0; ii < 8; ii++) {
      loadw(ii * 4 + 2 + grp, a1y, b2y);
      step(a1x, b2x, &hsu[(grp * 2 + 0) * 4096], ii * 4 + grp);
      if (ii < 7) loadw(ii * 4 + 4 + grp, a1x, b2x);
      step(a1y, b2y, &hsu[(grp * 2 + 1) * 4096], ii * 4 + 2 + grp);
    }
    __syncthreads();
    if (grp == 0) {
#pragma unroll
      for (int mt = 0; mt < 2; mt++)
#pragma unroll
        for (int nt = 0; nt < 2; nt++)
#pragma unroll
          for (int r = 0; r < 4; r++)
            ots[(wm * 32 + mt * 16 + quad * 4 + r) * 68 + wn * 32 + nt * 16 + l15]
                = acc[mt][nt][r];
    }
    __syncthreads();
    if (grp == 1) {
#pragma unroll
      for (int mt = 0; mt < 2; mt++)
#pragma unroll
        for (int nt = 0; nt < 2; nt++)
#pragma unroll
          for (int r = 0; r < 4; r++)
            ots[(wm * 32 + mt * 16 + quad * 4 + r) * 68 + wn * 32 + nt * 16 + l15]
                += acc[mt][nt][r];
    }
  }
  __syncthreads();
  // ======== residual + LN2 -> x1, xf, xs ========
  for (int i = 0; i < 8; i++) {
    int row = wave * 8 + i;
    size_t off = (size_t)(bx * 64 + row) * 64 + lane;
    float val = ots[row * 68 + lane] + xf[row * 64 + lane];
    float sum = val;
#pragma unroll
    for (int o = 32; o > 0; o >>= 1) sum += __shfl_xor(sum, o);
    float mean = sum * (1.f / 64.f);
    float d = val - mean;
    float sq = d * d;
#pragma unroll
    for (int o = 32; o > 0; o >>= 1) sq += __shfl_xor(sq, o);
    float xv = d * rsqrtf(sq * (1.f / 64.f) + 1e-5f) * ln2_s[lane] + ln2_b[lane];
    x1[off] = xv;
    xf[row * 64 + lane] = xv;
    xs[SW64(row, lane)] = (_Float16)xv;
  }
  __syncthreads();
  if (doqkv) {
    int grp = wave >> 2, w4 = wave & 3;
    int wm = w4 >> 1, wn = w4 & 1;
    half8 af[2][2];
#pragma unroll
    for (int mt = 0; mt < 2; mt++)
#pragma unroll
      for (int ks = 0; ks < 2; ks++)
        af[mt][ks] = *(const half8*)&xs[SW64(wm * 32 + mt * 16 + l15,
                                             ks * 32 + quad * 8)];
    for (int nb = grp; nb < 3; nb += 2)
      qkv_nb(af, wqkvf, bqkv, qout, kvbuf, (l + 1) & 1, bx, nb, wm, wn, lane);
  } else {
    if (tq == 15 && tid < 192) {
      int v = tid / 3, j = tid - v * 3;
      float a = bh[j];
      for (int e = 0; e < 64; e++) a += xf[v * 64 + e] * Wh[e * 3 + j];
      out[((size_t)(b * 64 + v)) * 3 + j] = a;
    }
  }
}

extern "C" void kernel_launch(void* const* d_in, const int* in_sizes, int n_in,
                              void* d_out, int out_size, void* d_ws, size_t ws_size,
                              hipStream_t stream) {
  const float* features = (const float*)d_in[0];
  const int*   ovtag    = (const int*)d_in[1];
  const int*   poiid    = (const int*)d_in[2];
  const float* W_raw    = (const float*)d_in[3];
  const float* b_raw    = (const float*)d_in[4];
  const float* pos_tab  = (const float*)d_in[5];
  const float* type_tab = (const float*)d_in[6];
  const float* poi_tab  = (const float*)d_in[7];
  const float* ov_tab   = (const float*)d_in[8];
  const float* W_comb   = (const float*)d_in[9];
  const float* b_comb   = (const float*)d_in[10];
  const float* Wqkv     = (const float*)d_in[11];
  const float* bqkv     = (const float*)d_in[12];
  const float* Wo       = (const float*)d_in[13];
  const float* bo       = (const float*)d_in[14];
  const float* ln1_s    = (const float*)d_in[15];
  const float* ln1_b    = (const float*)d_in[16];
  const float* W1       = (const float*)d_in[17];
  const float* b1       = (const float*)d_in[18];
  const float* W2       = (const float*)d_in[19];
  const float* b2       = (const float*)d_in[20];
  const float* ln2_s    = (const float*)d_in[21];
  const float* ln2_b    = (const float*)d_in[22];
  const float* W_head   = (const float*)d_in[23];
  const float* b_head   = (const float*)d_in[24];
  float* out = (float*)d_out;
  float* ws  = (float*)d_ws;

  float* zm = ws;                                       // BL
  float* x1 = zm + BL;                                  // BL*64 fp32
  _Float16* qbuf   = (_Float16*)(x1 + (size_t)BL * 64); // BL*64 head-major
  _Float16* kvbuf  = qbuf + (size_t)BL * 64;            // 2 sets x 2 x BL*64
  _Float16* wcombt = kvbuf + 4 * (size_t)BL * 64;       // 64*80
  _Float16* w1f    = wcombt + 5120;                     // NL*PERL
  _Float16* w2f    = w1f + (size_t)NLAYER * PERL;       // NL*PERL
  _Float16* wqkvf  = w2f + (size_t)NLAYER * PERL;       // NL*3*4096
  _Float16* wof    = wqkvf + (size_t)NLAYER * 3 * 4096; // NL*4096

  k_prep<<<274, 256, 0, stream>>>(W1, W2, Wqkv, Wo, W_comb,
                                  w1f, w2f, wqkvf, wof, wcombt);
  k_embqkv<<<256, 256, 0, stream>>>(features, ovtag, poiid, W_raw, b_raw,
                                    ov_tab, poi_tab, wcombt, b_comb,
                                    pos_tab, type_tab, x1, zm,
                                    wqkvf, bqkv, qbuf, kvbuf);
  for (int l = 0; l < NLAYER; l++) {
    int doqkv = (l < NLAYER - 1);
    k_layer3<<<256, 512, 0, stream>>>(
        qbuf, kvbuf, l,
        wof + (size_t)l * 4096, bo + l * EE, x1,
        ln1_s + l * EE, ln1_b + l * EE,
        w1f + (size_t)l * PERL, w2f + (size_t)l * PERL,
        b1 + l * DFF_, b2 + l * EE,
        ln2_s + l * EE, ln2_b + l * EE,
        wqkvf + (size_t)(l + 1 < NLAYER ? l + 1 : 0) * 3 * 4096,
        bqkv + (l + 1 < NLAYER ? l + 1 : 0) * 192,
        qbuf, doqkv, W_head, b_head, out, zm);
  }
}

// Round 14
// 337.425 us; speedup vs baseline: 1.4472x; 1.0082x over previous
//
#include <hip/hip_runtime.h>
#include <math.h>

#define BB 16
#define SS 16
#define VVV 64
#define EE 64
#define HHH 8
#define NLAYER 4
#define DFF_ 2048
#define LL 1024   /* S*V */
#define BL 16384  /* B*L */
#define PERL 131072  /* 64*2048 halves per layer of W1 (and W2); 32 tiles*4096 */

typedef __attribute__((ext_vector_type(8))) _Float16 half8;
typedef __attribute__((ext_vector_type(4))) _Float16 half4v;
typedef __attribute__((ext_vector_type(2))) _Float16 half2v;
typedef __attribute__((ext_vector_type(4))) float f32x4;

#if defined(__has_builtin)
#if __has_builtin(__builtin_amdgcn_fdot2)
#define HAVE_FDOT2 1
#endif
#endif

// XOR-swizzled index into row-major fp16 LDS tiles with 64-half (128 B) rows.
#define SW64(m, k)  (((m) << 6) + ((((k) >> 3) ^ ((m) & 7)) << 3) + ((k) & 7))

// Fragment-linear tile layout (64x64 fp16 = 8 frags of 512 halves):
//   A[m][k] -> frag = (m>>4)*2 + (k>>5); lane = ((k>>3)&3)*16 + (m&15); +(k&7)

__device__ __forceinline__ float dot8(half8 a, half8 b) {
  float s = 0.f;
#ifdef HAVE_FDOT2
#pragma unroll
  for (int j = 0; j < 4; j++) {
    half2v x = (half2v){a[2 * j], a[2 * j + 1]};
    half2v y = (half2v){b[2 * j], b[2 * j + 1]};
    s = __builtin_amdgcn_fdot2(x, y, s, false);
  }
#else
#pragma unroll
  for (int j = 0; j < 8; j++) s += (float)a[j] * (float)b[j];
#endif
  return s;
}

// ---------------- prep: weights -> fp16 fragment-linear tiles (one dispatch) ----------
__global__ __launch_bounds__(256) void k_prep(
    const float* __restrict__ W1, const float* __restrict__ W2,
    const float* __restrict__ Wqkv, const float* __restrict__ Wo,
    const float* __restrict__ Wcomb,
    _Float16* __restrict__ w1f, _Float16* __restrict__ w2f,
    _Float16* __restrict__ wqkvf, _Float16* __restrict__ wof,
    _Float16* __restrict__ wcombt)
{
  __shared__ float t[64 * 65];
  int bx = blockIdx.x;
  int cc = threadIdx.x & 63, rr = threadIdx.x >> 6;

  if (bx >= 272) {  // Wcomb [80][64] -> wcombt [64][80]
    int r0 = (bx - 272) * 64;
#pragma unroll
    for (int i = 0; i < 16; i++) {
      int r = i * 4 + rr;
      if (r0 + r < 80) t[r * 65 + cc] = Wcomb[(size_t)(r0 + r) * 64 + cc];
    }
    __syncthreads();
#pragma unroll
    for (int i = 0; i < 16; i++) {
      int c = i * 4 + rr;
      if (r0 + c < 80) wcombt[(size_t)cc * 80 + r0 + c] = (_Float16)t[c * 65 + cc];
    }
    return;
  }

  const float* src; _Float16* dst; int astr;
  if (bx < 128) {        // W1 [64 k][2048 hid]: tile g = hid block
    int l = bx >> 5, g = bx & 31;
    src = W1 + (size_t)l * PERL + g * 64; astr = 2048;
    dst = w1f + (size_t)(l * 32 + g) * 4096;
  } else if (bx < 256) { // W2 [2048 k][64 n]: tile g = k block
    int j = bx - 128; int l = j >> 5, g = j & 31;
    src = W2 + (size_t)l * PERL + (size_t)g * 64 * 64; astr = 64;
    dst = w2f + (size_t)(l * 32 + g) * 4096;
  } else if (bx < 268) { // Wqkv [64 k][192 n]: 3 tiles per layer
    int j = bx - 256; int l = j / 3, g = j % 3;
    src = Wqkv + (size_t)l * 64 * 192 + g * 64; astr = 192;
    dst = wqkvf + (size_t)(l * 3 + g) * 4096;
  } else {               // Wo [64 k][64 n]
    int l = bx - 268;
    src = Wo + (size_t)l * 4096; astr = 64;
    dst = wof + (size_t)l * 4096;
  }
#pragma unroll
  for (int i = 0; i < 16; i++) {
    int a = i * 4 + rr;
    t[cc * 65 + a] = src[(size_t)a * astr + cc];  // t[m][k] = S[k][m]
  }
  __syncthreads();
#pragma unroll
  for (int it = 0; it < 2; it++) {
    int c = threadIdx.x + it * 256;
    int frag = c >> 6, lane = c & 63;
    int m = (frag >> 1) * 16 + (lane & 15);
    int k0 = (frag & 1) * 32 + (lane >> 4) * 8;
    const float* tr = &t[m * 65 + k0];
    half8 h;
#pragma unroll
    for (int j = 0; j < 8; j++) h[j] = (_Float16)tr[j];
    *(half8*)&dst[(size_t)c * 8] = h;
  }
}

// ---- QKV GEMM into an LDS tile ([rb][col], SW64). Roles: wm,wn in {0,1} (4 waves) ----
__device__ __forceinline__ void qkv_tile(
    const half8 (&af)[2][2], const _Float16* __restrict__ bt,
    const float* __restrict__ bias_nb, _Float16* tile,
    int wm, int wn, int lane)
{
  int quad = lane >> 4, l15 = lane & 15;
  half8 bf[2][2];
#pragma unroll
  for (int nt = 0; nt < 2; nt++)
#pragma unroll
    for (int ks = 0; ks < 2; ks++)
      bf[nt][ks] = *(const half8*)&bt[(size_t)(((wn * 2 + nt) * 2 + ks) * 512) +
                                      lane * 8];
  f32x4 acc[2][2];
#pragma unroll
  for (int mt = 0; mt < 2; mt++)
#pragma unroll
    for (int nt = 0; nt < 2; nt++) {
      float bv = bias_nb[wn * 32 + nt * 16 + l15];
      acc[mt][nt] = (f32x4){bv, bv, bv, bv};
    }
#pragma unroll
  for (int ks = 0; ks < 2; ks++)
#pragma unroll
    for (int mt = 0; mt < 2; mt++)
#pragma unroll
      for (int nt = 0; nt < 2; nt++)
        acc[mt][nt] = __builtin_amdgcn_mfma_f32_16x16x32_f16(
            af[mt][ks], bf[nt][ks], acc[mt][nt], 0, 0, 0);
#pragma unroll
  for (int mt = 0; mt < 2; mt++)
#pragma unroll
    for (int nt = 0; nt < 2; nt++) {
      int col = wn * 32 + nt * 16 + l15;
#pragma unroll
      for (int r = 0; r < 4; r++) {
        int rb = wm * 32 + mt * 16 + quad * 4 + r;
        tile[SW64(rb, col)] = (_Float16)acc[mt][nt][r];
      }
    }
}

// ------- fused embed + comb GEMM + pos/type + QKV(layer0); XCD swizzle b = bx&15 -------
__global__ __launch_bounds__(256) void k_embqkv(
    const float* __restrict__ features, const int* __restrict__ ovtag,
    const int* __restrict__ poiid, const float* __restrict__ W_raw,
    const float* __restrict__ b_raw, const float* __restrict__ ov_tab,
    const float* __restrict__ poi_tab, const _Float16* __restrict__ wcombt,
    const float* __restrict__ b_comb, const float* __restrict__ pos_tab,
    const float* __restrict__ type_tab, float* __restrict__ x1,
    float* __restrict__ zm, const _Float16* __restrict__ wqkvf,
    const float* __restrict__ bqkv, _Float16* __restrict__ qbuf,
    _Float16* __restrict__ kvbuf)
{
  constexpr int KP = 104;
  __shared__ _Float16 As[64 * KP];
  __shared__ _Float16 Bs[64 * KP];
  __shared__ _Float16 xs[4096];
  int tid = threadIdx.x;
  int bx = blockIdx.x;
  int b = bx & 15, tq = bx >> 4;        // XCD-local: all blocks of batch b on XCD b%8
  int rowbase = b * 1024 + tq * 64;
  int wave = tid >> 6, lane = tid & 63, quad = lane >> 4, l15 = lane & 15;
  int wm = wave >> 1, wn = wave & 1;
  for (int p = tid; p < 1536; p += 256) {
    int r = p / 24, s = p - r * 24; int c = s * 4;
    int row = rowbase + r;
    float f0 = features[row * 3 + 0];
    float f1 = features[row * 3 + 1];
    float f2 = features[row * 3 + 2];
    if (s == 0) zm[row] = ((f0 + f1 + f2) == 0.f) ? 1.f : 0.f;
    half4v h;
#pragma unroll
    for (int j = 0; j < 4; j++) {
      int cc = c + j; float v;
      if (cc < 64) {
        v = b_raw[cc] + f0 * W_raw[cc] + f1 * W_raw[64 + cc] + f2 * W_raw[128 + cc];
      } else if (cc < 72) {
        int tt = ovtag[row]; v = (tt <= 0) ? 0.f : ov_tab[tt * 8 + cc - 64];
      } else if (cc < 80) {
        int tt = poiid[row]; v = (tt <= 0) ? 0.f : poi_tab[tt * 8 + cc - 72];
      } else v = 0.f;
      h[j] = (_Float16)v;
    }
    *(half4v*)&As[r * KP + c] = h;
  }
  for (int p = tid; p < 1536; p += 256) {
    int r = p / 24, s = p - r * 24; int c = s * 4;
    half4v h = (half4v){0, 0, 0, 0};
    if (c < 80) h = *(const half4v*)&wcombt[r * 80 + c];
    *(half4v*)&Bs[r * KP + c] = h;
  }
  __syncthreads();
  f32x4 acc[2][2];
#pragma unroll
  for (int mt = 0; mt < 2; mt++)
#pragma unroll
    for (int nt = 0; nt < 2; nt++) {
      float bv = b_comb[wn * 32 + nt * 16 + l15];
      acc[mt][nt] = (f32x4){bv, bv, bv, bv};
    }
#pragma unroll
  for (int ks = 0; ks < 3; ks++) {
    half8 af[2], bf[2];
#pragma unroll
    for (int mt = 0; mt < 2; mt++)
      af[mt] = *(const half8*)&As[(wm * 32 + mt * 16 + l15) * KP + ks * 32 + quad * 8];
#pragma unroll
    for (int nt = 0; nt < 2; nt++)
      bf[nt] = *(const half8*)&Bs[(wn * 32 + nt * 16 + l15) * KP + ks * 32 + quad * 8];
#pragma unroll
    for (int mt = 0; mt < 2; mt++)
#pragma unroll
      for (int nt = 0; nt < 2; nt++)
        acc[mt][nt] = __builtin_amdgcn_mfma_f32_16x16x32_f16(af[mt], bf[nt],
                                                             acc[mt][nt], 0, 0, 0);
  }
#pragma unroll
  for (int mt = 0; mt < 2; mt++)
#pragma unroll
    for (int nt = 0; nt < 2; nt++)
#pragma unroll
      for (int r = 0; r < 4; r++) {
        int lrow = wm * 32 + mt * 16 + quad * 4 + r;
        int row = rowbase + lrow;
        int col = wn * 32 + nt * 16 + l15;
        int l = row & (LL - 1);
        float v = acc[mt][nt][r] +
            pos_tab[(l >> 6) * 64 + col] + type_tab[(l & 63) * 64 + col];
        x1[(size_t)row * 64 + col] = v;
        xs[SW64(lrow, col)] = (_Float16)v;
      }
  __syncthreads();
  half8 af[2][2];
#pragma unroll
  for (int mt = 0; mt < 2; mt++)
#pragma unroll
    for (int ks = 0; ks < 2; ks++)
      af[mt][ks] = *(const half8*)&xs[SW64(wm * 32 + mt * 16 + l15,
                                           ks * 32 + quad * 8)];
  // QKV via LDS tile -> coalesced head-major writes (set 0)
  _Float16* tile = As;   // reuse (8 KB)
  for (int nb = 0; nb < 3; nb++) {
    __syncthreads();
    qkv_tile(af, wqkvf + (size_t)nb * 4096, bqkv + nb * 64, tile, wm, wn, lane);
    __syncthreads();
    _Float16* base = (nb == 0)
        ? qbuf + (size_t)(b * 8) * 8192
        : kvbuf + ((size_t)((nb - 1) * (BB * 8) + b * 8)) * 8192;
    for (int c = wave; c < 8; c += 4) {
      half8 val = *(const half8*)&tile[SW64(lane, c * 8)];
      *(half8*)&base[(size_t)c * 8192 + (tq * 64 + lane) * 8] = val;
    }
  }
}

// ---- per-layer merged kernel; XCD swizzle; coalesced q/k/v output via LDS tiles ----
__global__ __launch_bounds__(512, 4) void k_layer3(
    const _Float16* __restrict__ qbuf, _Float16* __restrict__ kvbuf, int l,
    const _Float16* __restrict__ wof, const float* __restrict__ bo,
    float* __restrict__ x1,
    const float* __restrict__ ln1_s, const float* __restrict__ ln1_b,
    const _Float16* __restrict__ w1f, const _Float16* __restrict__ w2f,
    const float* __restrict__ b1, const float* __restrict__ b2,
    const float* __restrict__ ln2_s, const float* __restrict__ ln2_b,
    const _Float16* __restrict__ wqkvf, const float* __restrict__ bqkv,
    _Float16* __restrict__ qout, int doqkv,
    const float* __restrict__ Wh, const float* __restrict__ bh,
    float* __restrict__ out, const float* __restrict__ zm)
{
  __shared__ float    xf[4096];              // 16 KB fp32 residual x
  __shared__ _Float16 xs[4096];              // 8 KB fp16 x, SW64
  __shared__ _Float16 qlds[4096];            // 8 KB attention output, frag-linear
  __shared__ float    zb[1024];              // 4 KB additive mask bias
  __shared__ __align__(16) float smem_u[8192];  // 32 KB: hs | ots | qkv tiles
  _Float16* hsu = (_Float16*)smem_u;
  float* ots = smem_u;

  int tid = threadIdx.x, bx = blockIdx.x;
  int wave = tid >> 6, lane = tid & 63;
  int quad = lane >> 4, l15 = lane & 15;
  int b = bx & 15, tq = bx >> 4;       // XCD-local mapping
  int rowbase = b * 1024 + tq * 64;

  // ======== attention (wave = head, lane = q-row) ========
  for (int p = tid; p < 1024; p += 512)
    zb[p] = (zm[b * LL + p] != 0.f) ? -1e30f : 0.f;
  __syncthreads();
  {
    int h = wave;
    half8 qh = *(const half8*)&qbuf[((size_t)(b * 8 + h) * 1024 +
                                     tq * 64 + lane) * 8];
    const _Float16* kb = kvbuf + ((size_t)((((l & 1) * 2 + 0) * (BB * 8)) +
                                           b * 8 + h)) * 8192;
    const _Float16* vb = kvbuf + ((size_t)((((l & 1) * 2 + 1) * (BB * 8)) +
                                           b * 8 + h)) * 8192;
    const float scale = 0.3535533905932738f;
    float m = -INFINITY, lsum = 0.f;
    float acc[8] = {0.f, 0.f, 0.f, 0.f, 0.f, 0.f, 0.f, 0.f};
    bool zmq = (zb[tq * 64 + lane] < -1.f);
    if (!zmq) {
      for (int g = 0; g < 16; g++) {     // same-t, wave-uniform keys
        half8 kk[4], vv[4]; float s[4];
#pragma unroll
        for (int j = 0; j < 4; j++) {
          int k = tq * 64 + g * 4 + j;
          kk[j] = *(const half8*)&kb[k * 8];
          vv[j] = *(const half8*)&vb[k * 8];
        }
#pragma unroll
        for (int j = 0; j < 4; j++)
          s[j] = dot8(qh, kk[j]) * scale + zb[tq * 64 + g * 4 + j];
        float gm = fmaxf(fmaxf(s[0], s[1]), fmaxf(s[2], s[3]));
        float nm = fmaxf(m, gm);
        float r = __expf(m - nm);
        float p0 = __expf(s[0] - nm), p1 = __expf(s[1] - nm);
        float p2 = __expf(s[2] - nm), p3 = __expf(s[3] - nm);
        lsum = lsum * r + (p0 + p1) + (p2 + p3);
#pragma unroll
        for (int d = 0; d < 8; d++)
          acc[d] = acc[d] * r + p0 * (float)vv[0][d] + p1 * (float)vv[1][d] +
                   p2 * (float)vv[2][d] + p3 * (float)vv[3][d];
        m = nm;
      }
      for (int g = 0; g < 4; g++) {      // same-v, coalesced
        half8 kk[4], vv[4]; float s[4];
#pragma unroll
        for (int j = 0; j < 4; j++) {
          int tt = g * 4 + j;
          int k = tt * 64 + lane;
          kk[j] = *(const half8*)&kb[k * 8];
          vv[j] = *(const half8*)&vb[k * 8];
          s[j] = (tt == tq) ? -1e30f : zb[k];
        }
#pragma unroll
        for (int j = 0; j < 4; j++)
          s[j] += dot8(qh, kk[j]) * scale;
        float gm = fmaxf(fmaxf(s[0], s[1]), fmaxf(s[2], s[3]));
        float nm = fmaxf(m, gm);
        float r = __expf(m - nm);
        float p0 = __expf(s[0] - nm), p1 = __expf(s[1] - nm);
        float p2 = __expf(s[2] - nm), p3 = __expf(s[3] - nm);
        lsum = lsum * r + (p0 + p1) + (p2 + p3);
#pragma unroll
        for (int d = 0; d < 8; d++)
          acc[d] = acc[d] * r + p0 * (float)vv[0][d] + p1 * (float)vv[1][d] +
                   p2 * (float)vv[2][d] + p3 * (float)vv[3][d];
        m = nm;
      }
    }
    float inv = 1.f / lsum;
    half8 o;
#pragma unroll
    for (int d = 0; d < 8; d++) o[d] = (_Float16)(acc[d] * inv);
    int frag = (lane >> 4) * 2 + (h >> 2);
    int fl = (h & 3) * 16 + (lane & 15);
    *(half8*)&qlds[frag * 512 + fl * 8] = o;
  }
  __syncthreads();
  // ======== o-proj -> ots ========
  {
    int wm = wave >> 1, wn = wave & 1;
    f32x4 acc[2];
#pragma unroll
    for (int nt = 0; nt < 2; nt++) {
      float bv = bo[wn * 32 + nt * 16 + l15];
      acc[nt] = (f32x4){bv, bv, bv, bv};
    }
#pragma unroll
    for (int ks = 0; ks < 2; ks++) {
      half8 af = *(const half8*)&qlds[(wm * 2 + ks) * 512 + lane * 8];
#pragma unroll
      for (int nt = 0; nt < 2; nt++) {
        half8 bf = *(const half8*)&wof[(size_t)(((wn * 2 + nt) * 2 + ks) * 512) +
                                       lane * 8];
        acc[nt] = __builtin_amdgcn_mfma_f32_16x16x32_f16(af, bf, acc[nt], 0, 0, 0);
      }
    }
#pragma unroll
    for (int nt = 0; nt < 2; nt++)
#pragma unroll
      for (int r = 0; r < 4; r++)
        ots[(wm * 16 + quad * 4 + r) * 68 + wn * 32 + nt * 16 + l15] = acc[nt][r];
  }
  __syncthreads();
  // ======== residual + LN1 ========
  for (int i = 0; i < 8; i++) {
    int row = wave * 8 + i;
    size_t off = (size_t)(rowbase + row) * 64 + lane;
    float val = ots[row * 68 + lane] + x1[off];
    float sum = val;
#pragma unroll
    for (int o = 32; o > 0; o >>= 1) sum += __shfl_xor(sum, o);
    float mean = sum * (1.f / 64.f);
    float d = val - mean;
    float sq = d * d;
#pragma unroll
    for (int o = 32; o > 0; o >>= 1) sq += __shfl_xor(sq, o);
    float xv = d * rsqrtf(sq * (1.f / 64.f) + 1e-5f) * ln1_s[lane] + ln1_b[lane];
    xf[row * 64 + lane] = xv;
    xs[SW64(row, lane)] = (_Float16)xv;
  }
  __syncthreads();
  // ======== FFN (2 groups x 4 waves; reg prefetch) ========
  {
    int grp = wave >> 2, w4 = wave & 3;
    int wm = w4 >> 1, wn = w4 & 1;
    half8 xb[2][2];
#pragma unroll
    for (int mt = 0; mt < 2; mt++)
#pragma unroll
      for (int ks = 0; ks < 2; ks++)
        xb[mt][ks] = *(const half8*)&xs[SW64(wn * 32 + mt * 16 + l15,
                                             ks * 32 + quad * 8)];
    f32x4 acc[2][2];
#pragma unroll
    for (int mt = 0; mt < 2; mt++)
#pragma unroll
      for (int nt = 0; nt < 2; nt++) {
        float bv = (grp == 0) ? b2[wn * 32 + nt * 16 + l15] : 0.f;
        acc[mt][nt] = (f32x4){bv, bv, bv, bv};
      }
    half8 a1x[2][2], b2x[2][2], a1y[2][2], b2y[2][2];
    auto loadw = [&](int g, half8 (&a1)[2][2], half8 (&b2w)[2][2]) {
      const _Float16* w1t_ = w1f + (size_t)g * 4096;
      const _Float16* w2t_ = w2f + (size_t)g * 4096;
#pragma unroll
      for (int ht = 0; ht < 2; ht++)
#pragma unroll
        for (int ks = 0; ks < 2; ks++)
          a1[ht][ks] = *(const half8*)&w1t_[(size_t)(((wm * 2 + ht) * 2 + ks) * 512)
                                            + lane * 8];
#pragma unroll
      for (int nt = 0; nt < 2; nt++)
#pragma unroll
        for (int ks = 0; ks < 2; ks++)
          b2w[nt][ks] = *(const half8*)&w2t_[(size_t)(((wn * 2 + nt) * 2 + ks) * 512)
                                             + lane * 8];
    };
    auto step = [&](const half8 (&a1)[2][2], const half8 (&b2w)[2][2],
                    _Float16* hsbuf, int g) {
      f32x4 hacc[2][2];
#pragma unroll
      for (int ht = 0; ht < 2; ht++)
#pragma unroll
        for (int mt = 0; mt < 2; mt++) hacc[ht][mt] = (f32x4){0.f, 0.f, 0.f, 0.f};
#pragma unroll
      for (int ks = 0; ks < 2; ks++)
#pragma unroll
        for (int ht = 0; ht < 2; ht++)
#pragma unroll
          for (int mt = 0; mt < 2; mt++)
            hacc[ht][mt] = __builtin_amdgcn_mfma_f32_16x16x32_f16(
                a1[ht][ks], xb[mt][ks], hacc[ht][mt], 0, 0, 0);
#pragma unroll
      for (int ht = 0; ht < 2; ht++) {
        float4 bb = *(const float4*)&b1[g * 64 + wm * 32 + ht * 16 + quad * 4];
#pragma unroll
        for (int mt = 0; mt < 2; mt++) {
          f32x4 hv = hacc[ht][mt];
          half4v hp = (half4v){
              (_Float16)fmaxf(hv[0] + bb.x, 0.f),
              (_Float16)fmaxf(hv[1] + bb.y, 0.f),
              (_Float16)fmaxf(hv[2] + bb.z, 0.f),
              (_Float16)fmaxf(hv[3] + bb.w, 0.f)};
          *(half4v*)&hsbuf[SW64(wn * 32 + mt * 16 + l15,
                                wm * 32 + ht * 16 + quad * 4)] = hp;
        }
      }
      __syncthreads();
#pragma unroll
      for (int ks = 0; ks < 2; ks++)
#pragma unroll
        for (int mt = 0; mt < 2; mt++) {
          half8 a2 = *(const half8*)&hsbuf[SW64(wm * 32 + mt * 16 + l15,
                                                ks * 32 + quad * 8)];
#pragma unroll
          for (int nt = 0; nt < 2; nt++)
            acc[mt][nt] = __builtin_amdgcn_mfma_f32_16x16x32_f16(
                a2, b2w[nt][ks], acc[mt][nt], 0, 0, 0);
        }
    };
    loadw(grp, a1x, b2x);
    for (int ii = 0; ii < 8; ii++) {
      loadw(ii * 4 + 2 + grp, a1y, b2y);
      step(a1x, b2x, &hsu[(grp * 2 + 0) * 4096], ii * 4 + grp);
      if (ii < 7) loadw(ii * 4 + 4 + grp, a1x, b2x);
      step(a1y, b2y, &hsu[(grp * 2 + 1) * 4096], ii * 4 + 2 + grp);
    }
    __syncthreads();
    if (grp == 0) {
#pragma unroll
      for (int mt = 0; mt < 2; mt++)
#pragma unroll
        for (int nt = 0; nt < 2; nt++)
#pragma unroll
          for (int r = 0; r < 4; r++)
            ots[(wm * 32 + mt * 16 + quad * 4 + r) * 68 + wn * 32 + nt * 16 + l15]
                = acc[mt][nt][r];
    }
    __syncthreads();
    if (grp == 1) {
#pragma unroll
      for (int mt = 0; mt < 2; mt++)
#pragma unroll
        for (int nt = 0; nt < 2; nt++)
#pragma unroll
          for (int r = 0; r < 4; r++)
            ots[(wm * 32 + mt * 16 + quad * 4 + r) * 68 + wn * 32 + nt * 16 + l15]
                += acc[mt][nt][r];
    }
  }
  __syncthreads();
  // ======== residual + LN2 -> x1, xf, xs ========
  for (int i = 0; i < 8; i++) {
    int row = wave * 8 + i;
    size_t off = (size_t)(rowbase + row) * 64 + lane;
    float val = ots[row * 68 + lane] + xf[row * 64 + lane];
    float sum = val;
#pragma unroll
    for (int o = 32; o > 0; o >>= 1) sum += __shfl_xor(sum, o);
    float mean = sum * (1.f / 64.f);
    float d = val - mean;
    float sq = d * d;
#pragma unroll
    for (int o = 32; o > 0; o >>= 1) sq += __shfl_xor(sq, o);
    float xv = d * rsqrtf(sq * (1.f / 64.f) + 1e-5f) * ln2_s[lane] + ln2_b[lane];
    x1[off] = xv;
    xf[row * 64 + lane] = xv;
    xs[SW64(row, lane)] = (_Float16)xv;
  }
  __syncthreads();    // ots reads done -> smem_u reusable as qkv tiles
  if (doqkv) {
    int grp = wave >> 2, w4 = wave & 3;
    int wm = w4 >> 1, wn = w4 & 1;
    half8 af[2][2];
#pragma unroll
    for (int mt = 0; mt < 2; mt++)
#pragma unroll
      for (int ks = 0; ks < 2; ks++)
        af[mt][ks] = *(const half8*)&xs[SW64(wm * 32 + mt * 16 + l15,
                                             ks * 32 + quad * 8)];
    int set = (l + 1) & 1;
    _Float16* t0 = hsu;          // q tile (then v tile)
    _Float16* t1 = hsu + 4096;   // k tile
    _Float16* qslot = qout + (size_t)(b * 8) * 8192;
    _Float16* kslot = kvbuf + ((size_t)((set * 2 + 0) * (BB * 8) + b * 8)) * 8192;
    _Float16* vslot = kvbuf + ((size_t)((set * 2 + 1) * (BB * 8) + b * 8)) * 8192;
    // round A: grp0 -> q into t0, grp1 -> k into t1
    qkv_tile(af, wqkvf + (size_t)grp * 4096, bqkv + grp * 64,
             grp ? t1 : t0, wm, wn, lane);
    __syncthreads();
    for (int c = wave; c < 16; c += 8) {
      int which = c >> 3, h = c & 7;
      half8 val = *(const half8*)&(which ? t1 : t0)[SW64(lane, h * 8)];
      _Float16* dst = which ? kslot : qslot;
      *(half8*)&dst[(size_t)h * 8192 + (tq * 64 + lane) * 8] = val;
    }
    __syncthreads();
    // round B: grp0 -> v into t0
    if (grp == 0)
      qkv_tile(af, wqkvf + (size_t)2 * 4096, bqkv + 2 * 64, t0, wm, wn, lane);
    __syncthreads();
    {
      int h = wave;
      half8 val = *(const half8*)&t0[SW64(lane, h * 8)];
      *(half8*)&vslot[(size_t)h * 8192 + (tq * 64 + lane) * 8] = val;
    }
  } else {
    if (tq == 15 && tid < 192) {
      int v = tid / 3, j = tid - v * 3;
      float a = bh[j];
      for (int e = 0; e < 64; e++) a += xf[v * 64 + e] * Wh[e * 3 + j];
      out[((size_t)(b * 64 + v)) * 3 + j] = a;
    }
  }
}

extern "C" void kernel_launch(void* const* d_in, const int* in_sizes, int n_in,
                              void* d_out, int out_size, void* d_ws, size_t ws_size,
                              hipStream_t stream) {
  const float* features = (const float*)d_in[0];
  const int*   ovtag    = (const int*)d_in[1];
  const int*   poiid    = (const int*)d_in[2];
  const float* W_raw    = (const float*)d_in[3];
  const float* b_raw    = (const float*)d_in[4];
  const float* pos_tab  = (const float*)d_in[5];
  const float* type_tab = (const float*)d_in[6];
  const float* poi_tab  = (const float*)d_in[7];
  const float* ov_tab   = (const float*)d_in[8];
  const float* W_comb   = (const float*)d_in[9];
  const float* b_comb   = (const float*)d_in[10];
  const float* Wqkv     = (const float*)d_in[11];
  const float* bqkv     = (const float*)d_in[12];
  const float* Wo       = (const float*)d_in[13];
  const float* bo       = (const float*)d_in[14];
  const float* ln1_s    = (const float*)d_in[15];
  const float* ln1_b    = (const float*)d_in[16];
  const float* W1       = (const float*)d_in[17];
  const float* b1       = (const float*)d_in[18];
  const float* W2       = (const float*)d_in[19];
  const float* b2       = (const float*)d_in[20];
  const float* ln2_s    = (const float*)d_in[21];
  const float* ln2_b    = (const float*)d_in[22];
  const float* W_head   = (const float*)d_in[23];
  const float* b_head   = (const float*)d_in[24];
  float* out = (float*)d_out;
  float* ws  = (float*)d_ws;

  float* zm = ws;                                       // BL
  float* x1 = zm + BL;                                  // BL*64 fp32
  _Float16* qbuf   = (_Float16*)(x1 + (size_t)BL * 64); // BL*64 head-major
  _Float16* kvbuf  = qbuf + (size_t)BL * 64;            // 2 sets x 2 x BL*64
  _Float16* wcombt = kvbuf + 4 * (size_t)BL * 64;       // 64*80
  _Float16* w1f    = wcombt + 5120;                     // NL*PERL
  _Float16* w2f    = w1f + (size_t)NLAYER * PERL;       // NL*PERL
  _Float16* wqkvf  = w2f + (size_t)NLAYER * PERL;       // NL*3*4096
  _Float16* wof    = wqkvf + (size_t)NLAYER * 3 * 4096; // NL*4096

  k_prep<<<274, 256, 0, stream>>>(W1, W2, Wqkv, Wo, W_comb,
                                  w1f, w2f, wqkvf, wof, wcombt);
  k_embqkv<<<256, 256, 0, stream>>>(features, ovtag, poiid, W_raw, b_raw,
                                    ov_tab, poi_tab, wcombt, b_comb,
                                    pos_tab, type_tab, x1, zm,
                                    wqkvf, bqkv, qbuf, kvbuf);
  for (int l = 0; l < NLAYER; l++) {
    int doqkv = (l < NLAYER - 1);
    k_layer3<<<256, 512, 0, stream>>>(
        qbuf, kvbuf, l,
        wof + (size_t)l * 4096, bo + l * EE, x1,
        ln1_s + l * EE, ln1_b + l * EE,
        w1f + (size_t)l * PERL, w2f + (size_t)l * PERL,
        b1 + l * DFF_, b2 + l * EE,
        ln2_s + l * EE, ln2_b + l * EE,
        wqkvf + (size_t)(l + 1 < NLAYER ? l + 1 : 0) * 3 * 4096,
        bqkv + (l + 1 < NLAYER ? l + 1 : 0) * 192,
        qbuf, doqkv, W_head, b_head, out, zm);
  }
}